// Round 12
// baseline (234.303 us; speedup 1.0000x reference)
//
#include <hip/hip_runtime.h>
#include <cstddef>

// ---------------------------------------------------------------------------
// SAGEBlock: 3-layer GraphSAGE (mean aggr), N=50000, E=800000.
//   h1 = relu(agg(x)@Wl1 + x@Wr1 + b1)              128 -> 256
//   h2 = relu(agg(h1@Wl2) + h1@Wr2 + b2)            256 -> 128
//   out= sigmoid(agg(h2@Wl3) + h2@Wr3 + b3)         128 -> 64
// R12: mgemm BN 64->128 (BM=128). BN=64 re-read A 4x across y-tiles
//     (~230MB avoidable traffic) and amortized only 16 MFMA per barrier;
//     BN=128 halves A re-reads, 32 MFMA/stage, LDS 32KB (5 blocks/CU cap).
//     CSR counting sort + F/4-lane agg unchanged (R10/R11 proven).
// ---------------------------------------------------------------------------

using frag  = __attribute__((ext_vector_type(8))) short;   // 8 bf16
using f32x4 = __attribute__((ext_vector_type(4))) float;

constexpr int PBITS = 9;                 // 512 nodes per partition
constexpr int PSZ   = 1 << PBITS;
constexpr int PMAX  = 128;               // max partitions (M <= 65536)

__device__ __forceinline__ ushort f2bf(float f) {
    union { float f; unsigned u; } v; v.f = f;
    unsigned r = v.u + 0x7FFF + ((v.u >> 16) & 1);   // RNE
    return (ushort)(r >> 16);
}
__device__ __forceinline__ float bf2f(ushort u) {
    union { unsigned u; float f; } v; v.u = ((unsigned)u) << 16;
    return v.f;
}

// ---------------- CSR build: counting sort by partition ----------------

__global__ __launch_bounds__(256)
void k_pcount(const int* __restrict__ dst, int* __restrict__ pcount, int E, int P) {
    __shared__ int h[PMAX];
    int t = threadIdx.x;
    if (t < P) h[t] = 0;
    __syncthreads();
    int base = blockIdx.x * 4096;
    int n = min(4096, E - base);
    for (int i = t; i < n; i += 256)
        atomicAdd(&h[dst[base + i] >> PBITS], 1);
    __syncthreads();
    if (t < P && h[t]) atomicAdd(&pcount[t], h[t]);
}

__global__ void k_pscan(const int* __restrict__ pcount, int* __restrict__ pbase,
                        int* __restrict__ pcursor, int P) {
    if (threadIdx.x == 0) {
        int run = 0;
        for (int p = 0; p < P; ++p) { pbase[p] = run; pcursor[p] = run; run += pcount[p]; }
        pbase[P] = run;
    }
}

__global__ __launch_bounds__(256)
void k_scatter(const int* __restrict__ src, const int* __restrict__ dst,
               int* __restrict__ pcursor, unsigned* __restrict__ pairs, int E, int P) {
    __shared__ int h[PMAX];
    __shared__ int off[PMAX];
    int t = threadIdx.x;
    if (t < P) h[t] = 0;
    __syncthreads();
    int base = blockIdx.x * 4096;
    int pp[16]; int pr[16]; unsigned pk[16];
    #pragma unroll
    for (int ii = 0; ii < 16; ++ii) {          // static index -> stays in VGPRs
        int idx = base + ii * 256 + t;
        bool v = idx < E;
        int d = v ? dst[idx] : 0;
        int p = d >> PBITS;
        pp[ii] = v ? p : -1;
        pr[ii] = v ? atomicAdd(&h[p], 1) : 0;
        pk[ii] = v ? ((unsigned)src[idx] | ((unsigned)(d & (PSZ - 1)) << 16)) : 0u;
    }
    __syncthreads();
    if (t < P && h[t]) off[t] = atomicAdd(&pcursor[t], h[t]);
    __syncthreads();
    #pragma unroll
    for (int ii = 0; ii < 16; ++ii)
        if (pp[ii] >= 0) pairs[off[pp[ii]] + pr[ii]] = pk[ii];
}

__global__ __launch_bounds__(256)
void k_build(const unsigned* __restrict__ pairs, const int* __restrict__ pbase,
             int* __restrict__ deg, int* __restrict__ row_start,
             ushort* __restrict__ csr16, int M) {
    __shared__ int cnt[PSZ];
    __shared__ int ls[PSZ];
    __shared__ int fil[PSZ];
    __shared__ int ws[256];
    int pid = blockIdx.x;
    int t = threadIdx.x;
    int n0 = pid << PBITS;
    int L = min(PSZ, M - n0);
    int wb = pbase[pid], we = pbase[pid + 1];
    int ne = we - wb;
    for (int j = t; j < PSZ; j += 256) { cnt[j] = 0; fil[j] = 0; }
    __syncthreads();
    for (int i = t; i < ne; i += 256)
        atomicAdd(&cnt[pairs[wb + i] >> 16], 1);
    __syncthreads();
    int a = cnt[2 * t], b = cnt[2 * t + 1];
    ws[t] = a + b;
    __syncthreads();
    for (int o = 1; o < 256; o <<= 1) {
        int v = (t >= o) ? ws[t - o] : 0;
        __syncthreads();
        ws[t] += v;
        __syncthreads();
    }
    int excl = (t > 0) ? ws[t - 1] : 0;
    ls[2 * t] = excl; ls[2 * t + 1] = excl + a;
    __syncthreads();
    for (int j = t; j < L; j += 256) {
        deg[n0 + j] = cnt[j];
        row_start[n0 + j] = wb + ls[j];
    }
    for (int i = t; i < ne; i += 256) {
        unsigned pk = pairs[wb + i];
        int ln = pk >> 16;
        int pos = wb + ls[ln] + atomicAdd(&fil[ln], 1);
        csr16[pos] = (ushort)(pk & 0xFFFFu);
    }
}

// ---------------- dtype converts ----------------

__global__ void k_cvt_x(const float* __restrict__ in, ushort* __restrict__ out, int n4) {
    int i = blockIdx.x * blockDim.x + threadIdx.x;
    if (i < n4) {
        float4 v = ((const float4*)in)[i];
        ushort4 o; o.x = f2bf(v.x); o.y = f2bf(v.y); o.z = f2bf(v.z); o.w = f2bf(v.w);
        ((ushort4*)out)[i] = o;
    }
}

struct CvtDesc {
    const float* s[6];
    ushort*      d[6];
    int K[6];
    int N[6];
};

__global__ void k_cvt_w6(CvtDesc c) {
    int wi = blockIdx.y;
    int t = blockIdx.x * blockDim.x + threadIdx.x;
    int K = c.K[wi], N = c.N[wi];
    if (t < K * N) {
        int k = t / N, n = t % N;
        c.d[wi][(size_t)n * K + k] = f2bf(c.s[wi][t]);
    }
}

// ---------------- mean aggregation + fused epilogue ----------------
// F/4 lanes per node, ushort4 (8B) per lane.
// EPI: 0 = plain bf16 out; 1 = relu(agg+u+b) bf16 out; 2 = sigmoid(agg+u+b) f32 out

template <int F, int EPI>
__global__ __launch_bounds__(256)
void agg_bf(const ushort* __restrict__ in, const ushort* __restrict__ csr16,
            const int* __restrict__ row_start, const int* __restrict__ deg,
            const ushort* __restrict__ u, const float* __restrict__ bias,
            void* __restrict__ out, int nN) {
    constexpr int GPL = F / 4;                 // lanes per node
    constexpr int NPB = 256 / GPL;             // nodes per block
    int gid  = threadIdx.x / GPL;
    int li   = threadIdx.x % GPL;
    int node = blockIdx.x * NPB + gid;
    bool valid = node < nN;
    int start = valid ? row_start[node] : 0;
    int d     = valid ? deg[node] : 0;
    float a0 = 0.f, a1 = 0.f, a2 = 0.f, a3 = 0.f;

    auto gat = [&](int j) {
        int s = csr16[start + j];
        ushort4 uv = *(const ushort4*)(in + (size_t)s * F + li * 4);
        a0 += bf2f(uv.x); a1 += bf2f(uv.y); a2 += bf2f(uv.z); a3 += bf2f(uv.w);
    };

    int j = 0;
    for (; j + 8 <= d; j += 8) {
        gat(j); gat(j+1); gat(j+2); gat(j+3);
        gat(j+4); gat(j+5); gat(j+6); gat(j+7);
    }
    for (; j + 2 <= d; j += 2) { gat(j); gat(j+1); }
    for (; j < d; ++j) gat(j);

    if (!valid) return;
    float inv = 1.f / (float)(d > 0 ? d : 1);
    a0 *= inv; a1 *= inv; a2 *= inv; a3 *= inv;

    size_t o4 = (size_t)node * F + li * 4;
    if constexpr (EPI == 0) {
        ushort4 o; o.x = f2bf(a0); o.y = f2bf(a1); o.z = f2bf(a2); o.w = f2bf(a3);
        *(ushort4*)((ushort*)out + o4) = o;
    } else {
        ushort4 uv = *(const ushort4*)(u + o4);
        float4 bv = *(const float4*)(bias + li * 4);
        a0 += bf2f(uv.x) + bv.x;
        a1 += bf2f(uv.y) + bv.y;
        a2 += bf2f(uv.z) + bv.z;
        a3 += bf2f(uv.w) + bv.w;
        if constexpr (EPI == 1) {
            ushort4 o;
            o.x = f2bf(fmaxf(a0, 0.f)); o.y = f2bf(fmaxf(a1, 0.f));
            o.z = f2bf(fmaxf(a2, 0.f)); o.w = f2bf(fmaxf(a3, 0.f));
            *(ushort4*)((ushort*)out + o4) = o;
        } else {
            float4 o;
            o.x = 1.f / (1.f + __expf(-a0)); o.y = 1.f / (1.f + __expf(-a1));
            o.z = 1.f / (1.f + __expf(-a2)); o.w = 1.f / (1.f + __expf(-a3));
            *(float4*)((float*)out + o4) = o;
        }
    }
}

// ---------------- bf16 MFMA GEMM (BK=64 loop), split-output epilogue --------
// C[M,N] = act( A1@B1^T (+ A2@B2^T) (+ bias) ); col < nsplit -> C1, else C2.
// A: [M][K] bf16. B: [N][K] bf16 (pre-transposed). LDS XOR-swizzled.

template <int BM, int BN, int WM, int WN, int ACT>
__global__ __launch_bounds__(WM * WN * 64)
void mgemm(const ushort* __restrict__ A1, const ushort* __restrict__ B1, int K1,
           const ushort* __restrict__ A2, const ushort* __restrict__ B2, int K2,
           const float* __restrict__ bias,
           ushort* __restrict__ C1, int ld1,
           ushort* __restrict__ C2, int ld2, int nsplit,
           int M, int N) {
    constexpr int NT = WM * WN * 64;
    constexpr int MF = BM / (WM * 16);
    constexpr int NF = BN / (WN * 16);
    __shared__ char lds[(BM + BN) * 128];     // rows x 64 bf16
    char* As = lds;
    char* Bs = lds + BM * 128;

    const int tid  = threadIdx.x;
    const int lane = tid & 63;
    const int wid  = tid >> 6;
    const int wm   = wid % WM, wn = wid / WM;
    const int bm   = blockIdx.x * BM;
    const int bn   = blockIdx.y * BN;
    const int l15  = lane & 15;
    const int lhi  = lane >> 4;

    f32x4 acc[MF][NF] = {};

    for (int pass = 0; pass < 2; ++pass) {
        const ushort* A = pass ? A2 : A1;
        const ushort* B = pass ? B2 : B1;
        const int K = pass ? K2 : K1;
        if (A == nullptr) continue;
        for (int k0 = 0; k0 < K; k0 += 64) {
            #pragma unroll
            for (int it = 0; it < BM * 8 / NT; ++it) {       // stage A
                int flat = it * NT + tid;
                int row = flat >> 3;
                int cb = (flat & 7) * 16;
                frag v = {};
                int gr = bm + row;
                if (gr < M) v = *(const frag*)(A + (size_t)gr * K + k0 + (flat & 7) * 8);
                *(frag*)(As + row * 128 + (cb ^ ((row & 7) << 4))) = v;
            }
            #pragma unroll
            for (int it = 0; it < BN * 8 / NT; ++it) {       // stage B
                int flat = it * NT + tid;
                int row = flat >> 3;
                int cb = (flat & 7) * 16;
                frag v = *(const frag*)(B + (size_t)(bn + row) * K + k0 + (flat & 7) * 8);
                *(frag*)(Bs + row * 128 + (cb ^ ((row & 7) << 4))) = v;
            }
            __syncthreads();
            #pragma unroll
            for (int ks = 0; ks < 2; ++ks) {
                const int kb = ks * 64 + lhi * 16;
                frag a[MF], b[NF];
                #pragma unroll
                for (int mf = 0; mf < MF; ++mf) {
                    int row = wm * MF * 16 + mf * 16 + l15;
                    a[mf] = *(const frag*)(As + row * 128 + (kb ^ ((row & 7) << 4)));
                }
                #pragma unroll
                for (int nf = 0; nf < NF; ++nf) {
                    int row = wn * NF * 16 + nf * 16 + l15;
                    b[nf] = *(const frag*)(Bs + row * 128 + (kb ^ ((row & 7) << 4)));
                }
                #pragma unroll
                for (int mf = 0; mf < MF; ++mf)
                    #pragma unroll
                    for (int nf = 0; nf < NF; ++nf)
                        acc[mf][nf] = __builtin_amdgcn_mfma_f32_16x16x32_bf16(
                            a[mf], b[nf], acc[mf][nf], 0, 0, 0);
            }
            __syncthreads();
        }
    }

    #pragma unroll
    for (int mf = 0; mf < MF; ++mf) {
        #pragma unroll
        for (int r = 0; r < 4; ++r) {
            int gm = bm + wm * MF * 16 + mf * 16 + lhi * 4 + r;
            if (gm >= M) continue;
            #pragma unroll
            for (int nf = 0; nf < NF; ++nf) {
                int gn = bn + wn * NF * 16 + nf * 16 + l15;
                float v = acc[mf][nf][r];
                if (bias) v += bias[gn];
                if (ACT == 1) v = fmaxf(v, 0.f);
                ushort o = f2bf(v);
                if (gn < nsplit) C1[(size_t)gm * ld1 + gn] = o;
                else             C2[(size_t)gm * ld2 + (gn - nsplit)] = o;
            }
        }
    }
}

// ---------------------------------------------------------------------------

extern "C" void kernel_launch(void* const* d_in, const int* in_sizes, int n_in,
                              void* d_out, int out_size, void* d_ws, size_t ws_size,
                              hipStream_t stream) {
    const float* x   = (const float*)d_in[0];
    const int*   ei  = (const int*)d_in[1];
    const float* Wl1 = (const float*)d_in[2];
    const float* Wr1 = (const float*)d_in[3];
    const float* b1  = (const float*)d_in[4];
    const float* Wl2 = (const float*)d_in[5];
    const float* Wr2 = (const float*)d_in[6];
    const float* b2  = (const float*)d_in[7];
    const float* Wl3 = (const float*)d_in[8];
    const float* Wr3 = (const float*)d_in[9];
    const float* b3  = (const float*)d_in[10];

    const int M = in_sizes[0] / 128;   // 50000
    const int E = in_sizes[1] / 2;     // 800000
    const int P = (M + PSZ - 1) / PSZ; // 98 partitions
    const int* src = ei;
    const int* dst = ei + E;

    char* w = (char*)d_ws;
    auto alloc = [&](size_t bytes) -> void* {
        void* p = (void*)w;
        w += (bytes + 255) & ~(size_t)255;
        return p;
    };
    int* pcount    = (int*)alloc((size_t)PMAX * 4);
    int* pbase     = (int*)alloc((size_t)(PMAX + 1) * 4);
    int* pcursor   = (int*)alloc((size_t)PMAX * 4);
    unsigned* pairs = (unsigned*)alloc((size_t)E * 4);
    ushort* csr16  = (ushort*)alloc((size_t)E * 2);
    int* deg       = (int*)alloc((size_t)M * 4);
    int* row_start = (int*)alloc((size_t)M * 4);
    ushort* Wl1t   = (ushort*)alloc(256 * 128 * 2);       // [256][128]
    ushort* Wr1t   = (ushort*)alloc(256 * 128 * 2);       // [256][128]
    ushort* Wcat2T = (ushort*)alloc(256 * 256 * 2);       // [256][256]: Wl2|Wr2 rows
    ushort* Wcat3T = (ushort*)alloc(128 * 128 * 2);       // [128][128]: Wl3|Wr3 rows
    ushort* bufA = (ushort*)alloc((size_t)M * 128 * 2);   // x_bf -> t2 -> t3
    ushort* bufB = (ushort*)alloc((size_t)M * 128 * 2);   // aggx -> h2
    ushort* bufH = (ushort*)alloc((size_t)M * 256 * 2);   // h1
    ushort* bufC = (ushort*)alloc((size_t)M * 128 * 2);   // u2 -> u3
    (void)ws_size; (void)n_in; (void)out_size;

    ushort* x_bf = bufA; ushort* t2 = bufA; ushort* t3 = bufA;
    ushort* aggx = bufB; ushort* h2 = bufB;
    ushort* h1 = bufH;
    ushort* u2 = bufC;   ushort* u3 = bufC;

    // CSR build: only pcount needs zeroing (<=512B)
    hipMemsetAsync(pcount, 0, (size_t)PMAX * 4, stream);
    const int nchunk = (E + 4095) / 4096;     // 196
    k_pcount<<<nchunk, 256, 0, stream>>>(dst, pcount, E, P);
    k_pscan<<<1, 64, 0, stream>>>(pcount, pbase, pcursor, P);
    k_scatter<<<nchunk, 256, 0, stream>>>(src, dst, pcursor, pairs, E, P);
    k_build<<<P, 256, 0, stream>>>(pairs, pbase, deg, row_start, csr16, M);

    // converts
    k_cvt_x<<<(M * 128 / 4 + 255) / 256, 256, 0, stream>>>(x, x_bf, M * 128 / 4);
    CvtDesc cd;
    cd.s[0] = Wl1; cd.d[0] = Wl1t;             cd.K[0] = 128; cd.N[0] = 256;
    cd.s[1] = Wr1; cd.d[1] = Wr1t;             cd.K[1] = 128; cd.N[1] = 256;
    cd.s[2] = Wl2; cd.d[2] = Wcat2T;           cd.K[2] = 256; cd.N[2] = 128;
    cd.s[3] = Wr2; cd.d[3] = Wcat2T + 128*256; cd.K[3] = 256; cd.N[3] = 128;
    cd.s[4] = Wl3; cd.d[4] = Wcat3T;           cd.K[4] = 128; cd.N[4] = 64;
    cd.s[5] = Wr3; cd.d[5] = Wcat3T + 64*128;  cd.K[5] = 128; cd.N[5] = 64;
    k_cvt_w6<<<dim3(128, 6), 256, 0, stream>>>(cd);

    const int gm128 = (M + 127) / 128;        // 391
    const int ga128 = (M + 7) / 8;            // 6250 (F=128: 8 nodes/block)
    const int ga64  = (M + 15) / 16;          // 3125 (F=64: 16 nodes/block)

    // ---- layer 1: aggx = agg(x); h1 = relu(aggx@Wl1 + x@Wr1 + b1)
    agg_bf<128, 0><<<ga128, 256, 0, stream>>>(x_bf, csr16, row_start, deg,
                                              nullptr, nullptr, aggx, M);
    mgemm<128, 128, 2, 2, 1><<<dim3(gm128, 2), 256, 0, stream>>>(
        aggx, Wl1t, 128, x_bf, Wr1t, 128, b1,
        h1, 256, nullptr, 0, 256, M, 256);

    // ---- layer 2: [t2|u2] = h1@Wcat2; h2 = relu(agg(t2) + u2 + b2)
    mgemm<128, 128, 2, 2, 0><<<dim3(gm128, 2), 256, 0, stream>>>(
        h1, Wcat2T, 256, nullptr, nullptr, 0, nullptr,
        t2, 128, u2, 128, 128, M, 256);
    agg_bf<128, 1><<<ga128, 256, 0, stream>>>(t2, csr16, row_start, deg,
                                              u2, b2, h2, M);

    // ---- layer 3: [t3|u3] = h2@Wcat3; out = sigmoid(agg(t3) + u3 + b3)
    mgemm<128, 128, 2, 2, 0><<<dim3(gm128, 1), 256, 0, stream>>>(
        h2, Wcat3T, 128, nullptr, nullptr, 0, nullptr,
        t3, 64, u3, 64, 64, M, 128);
    agg_bf<64, 2><<<ga64, 256, 0, stream>>>(t3, csr16, row_start, deg,
                                            u3, b3, (float*)d_out, M);
}

// Round 13
// 215.719 us; speedup vs baseline: 1.0861x; 1.0861x over previous
//
#include <hip/hip_runtime.h>
#include <cstddef>

// ---------------------------------------------------------------------------
// SAGEBlock: 3-layer GraphSAGE (mean aggr), N=50000, E=800000.
//   h1 = relu(agg(x)@Wl1 + x@Wr1 + b1)              128 -> 256
//   h2 = relu(agg(h1@Wl2) + h1@Wr2 + b2)            256 -> 128
//   out= sigmoid(agg(h2@Wl3) + h2@Wr3 + b3)         128 -> 64
// R13: BN back to 64 (R12's BN=128 halved the grid -> latency-bound, -17us).
//     mgemm staging via global_load_lds width=16: linear LDS dest, inverse-
//     XOR pre-swizzled global source (rule #21), swizzled read unchanged.
//     Removes the global->VGPR->ds_write round-trip from the stage path.
// ---------------------------------------------------------------------------

using frag  = __attribute__((ext_vector_type(8))) short;   // 8 bf16
using f32x4 = __attribute__((ext_vector_type(4))) float;

constexpr int PBITS = 9;                 // 512 nodes per partition
constexpr int PSZ   = 1 << PBITS;
constexpr int PMAX  = 128;               // max partitions (M <= 65536)

__device__ __forceinline__ ushort f2bf(float f) {
    union { float f; unsigned u; } v; v.f = f;
    unsigned r = v.u + 0x7FFF + ((v.u >> 16) & 1);   // RNE
    return (ushort)(r >> 16);
}
__device__ __forceinline__ float bf2f(ushort u) {
    union { unsigned u; float f; } v; v.u = ((unsigned)u) << 16;
    return v.f;
}

// ---------------- CSR build: counting sort by partition ----------------

__global__ __launch_bounds__(256)
void k_pcount(const int* __restrict__ dst, int* __restrict__ pcount, int E, int P) {
    __shared__ int h[PMAX];
    int t = threadIdx.x;
    if (t < P) h[t] = 0;
    __syncthreads();
    int base = blockIdx.x * 4096;
    int n = min(4096, E - base);
    for (int i = t; i < n; i += 256)
        atomicAdd(&h[dst[base + i] >> PBITS], 1);
    __syncthreads();
    if (t < P && h[t]) atomicAdd(&pcount[t], h[t]);
}

__global__ void k_pscan(const int* __restrict__ pcount, int* __restrict__ pbase,
                        int* __restrict__ pcursor, int P) {
    if (threadIdx.x == 0) {
        int run = 0;
        for (int p = 0; p < P; ++p) { pbase[p] = run; pcursor[p] = run; run += pcount[p]; }
        pbase[P] = run;
    }
}

__global__ __launch_bounds__(256)
void k_scatter(const int* __restrict__ src, const int* __restrict__ dst,
               int* __restrict__ pcursor, unsigned* __restrict__ pairs, int E, int P) {
    __shared__ int h[PMAX];
    __shared__ int off[PMAX];
    int t = threadIdx.x;
    if (t < P) h[t] = 0;
    __syncthreads();
    int base = blockIdx.x * 4096;
    int pp[16]; int pr[16]; unsigned pk[16];
    #pragma unroll
    for (int ii = 0; ii < 16; ++ii) {          // static index -> stays in VGPRs
        int idx = base + ii * 256 + t;
        bool v = idx < E;
        int d = v ? dst[idx] : 0;
        int p = d >> PBITS;
        pp[ii] = v ? p : -1;
        pr[ii] = v ? atomicAdd(&h[p], 1) : 0;
        pk[ii] = v ? ((unsigned)src[idx] | ((unsigned)(d & (PSZ - 1)) << 16)) : 0u;
    }
    __syncthreads();
    if (t < P && h[t]) off[t] = atomicAdd(&pcursor[t], h[t]);
    __syncthreads();
    #pragma unroll
    for (int ii = 0; ii < 16; ++ii)
        if (pp[ii] >= 0) pairs[off[pp[ii]] + pr[ii]] = pk[ii];
}

__global__ __launch_bounds__(256)
void k_build(const unsigned* __restrict__ pairs, const int* __restrict__ pbase,
             int* __restrict__ deg, int* __restrict__ row_start,
             ushort* __restrict__ csr16, int M) {
    __shared__ int cnt[PSZ];
    __shared__ int ls[PSZ];
    __shared__ int fil[PSZ];
    __shared__ int ws[256];
    int pid = blockIdx.x;
    int t = threadIdx.x;
    int n0 = pid << PBITS;
    int L = min(PSZ, M - n0);
    int wb = pbase[pid], we = pbase[pid + 1];
    int ne = we - wb;
    for (int j = t; j < PSZ; j += 256) { cnt[j] = 0; fil[j] = 0; }
    __syncthreads();
    for (int i = t; i < ne; i += 256)
        atomicAdd(&cnt[pairs[wb + i] >> 16], 1);
    __syncthreads();
    int a = cnt[2 * t], b = cnt[2 * t + 1];
    ws[t] = a + b;
    __syncthreads();
    for (int o = 1; o < 256; o <<= 1) {
        int v = (t >= o) ? ws[t - o] : 0;
        __syncthreads();
        ws[t] += v;
        __syncthreads();
    }
    int excl = (t > 0) ? ws[t - 1] : 0;
    ls[2 * t] = excl; ls[2 * t + 1] = excl + a;
    __syncthreads();
    for (int j = t; j < L; j += 256) {
        deg[n0 + j] = cnt[j];
        row_start[n0 + j] = wb + ls[j];
    }
    for (int i = t; i < ne; i += 256) {
        unsigned pk = pairs[wb + i];
        int ln = pk >> 16;
        int pos = wb + ls[ln] + atomicAdd(&fil[ln], 1);
        csr16[pos] = (ushort)(pk & 0xFFFFu);
    }
}

// ---------------- dtype converts ----------------

__global__ void k_cvt_x(const float* __restrict__ in, ushort* __restrict__ out, int n4) {
    int i = blockIdx.x * blockDim.x + threadIdx.x;
    if (i < n4) {
        float4 v = ((const float4*)in)[i];
        ushort4 o; o.x = f2bf(v.x); o.y = f2bf(v.y); o.z = f2bf(v.z); o.w = f2bf(v.w);
        ((ushort4*)out)[i] = o;
    }
}

struct CvtDesc {
    const float* s[6];
    ushort*      d[6];
    int K[6];
    int N[6];
};

__global__ void k_cvt_w6(CvtDesc c) {
    int wi = blockIdx.y;
    int t = blockIdx.x * blockDim.x + threadIdx.x;
    int K = c.K[wi], N = c.N[wi];
    if (t < K * N) {
        int k = t / N, n = t % N;
        c.d[wi][(size_t)n * K + k] = f2bf(c.s[wi][t]);
    }
}

// ---------------- mean aggregation + fused epilogue ----------------
// F/4 lanes per node, ushort4 (8B) per lane.
// EPI: 0 = plain bf16 out; 1 = relu(agg+u+b) bf16 out; 2 = sigmoid(agg+u+b) f32 out

template <int F, int EPI>
__global__ __launch_bounds__(256)
void agg_bf(const ushort* __restrict__ in, const ushort* __restrict__ csr16,
            const int* __restrict__ row_start, const int* __restrict__ deg,
            const ushort* __restrict__ u, const float* __restrict__ bias,
            void* __restrict__ out, int nN) {
    constexpr int GPL = F / 4;                 // lanes per node
    constexpr int NPB = 256 / GPL;             // nodes per block
    int gid  = threadIdx.x / GPL;
    int li   = threadIdx.x % GPL;
    int node = blockIdx.x * NPB + gid;
    bool valid = node < nN;
    int start = valid ? row_start[node] : 0;
    int d     = valid ? deg[node] : 0;
    float a0 = 0.f, a1 = 0.f, a2 = 0.f, a3 = 0.f;

    auto gat = [&](int j) {
        int s = csr16[start + j];
        ushort4 uv = *(const ushort4*)(in + (size_t)s * F + li * 4);
        a0 += bf2f(uv.x); a1 += bf2f(uv.y); a2 += bf2f(uv.z); a3 += bf2f(uv.w);
    };

    int j = 0;
    for (; j + 8 <= d; j += 8) {
        gat(j); gat(j+1); gat(j+2); gat(j+3);
        gat(j+4); gat(j+5); gat(j+6); gat(j+7);
    }
    for (; j + 2 <= d; j += 2) { gat(j); gat(j+1); }
    for (; j < d; ++j) gat(j);

    if (!valid) return;
    float inv = 1.f / (float)(d > 0 ? d : 1);
    a0 *= inv; a1 *= inv; a2 *= inv; a3 *= inv;

    size_t o4 = (size_t)node * F + li * 4;
    if constexpr (EPI == 0) {
        ushort4 o; o.x = f2bf(a0); o.y = f2bf(a1); o.z = f2bf(a2); o.w = f2bf(a3);
        *(ushort4*)((ushort*)out + o4) = o;
    } else {
        ushort4 uv = *(const ushort4*)(u + o4);
        float4 bv = *(const float4*)(bias + li * 4);
        a0 += bf2f(uv.x) + bv.x;
        a1 += bf2f(uv.y) + bv.y;
        a2 += bf2f(uv.z) + bv.z;
        a3 += bf2f(uv.w) + bv.w;
        if constexpr (EPI == 1) {
            ushort4 o;
            o.x = f2bf(fmaxf(a0, 0.f)); o.y = f2bf(fmaxf(a1, 0.f));
            o.z = f2bf(fmaxf(a2, 0.f)); o.w = f2bf(fmaxf(a3, 0.f));
            *(ushort4*)((ushort*)out + o4) = o;
        } else {
            float4 o;
            o.x = 1.f / (1.f + __expf(-a0)); o.y = 1.f / (1.f + __expf(-a1));
            o.z = 1.f / (1.f + __expf(-a2)); o.w = 1.f / (1.f + __expf(-a3));
            *(float4*)((float*)out + o4) = o;
        }
    }
}

// ---------------- bf16 MFMA GEMM (BK=64 loop), gload_lds staging ------------
// C[M,N] = act( A1@B1^T (+ A2@B2^T) (+ bias) ); col < nsplit -> C1, else C2.
// A: [M][K] bf16. B: [N][K] bf16 (pre-transposed).
// Staging: global_load_lds width=16, linear LDS dest; the XOR swizzle is
// pre-applied on the per-lane GLOBAL source (gfc = fc ^ (row&7)), so the
// swizzled ds_read side is unchanged (LDS byte b holds global byte
// b ^ ((row&7)<<4), identical to the old reg-staged layout).

__device__ __forceinline__ void gload16(const ushort* gp, char* lp) {
    __builtin_amdgcn_global_load_lds(
        (const __attribute__((address_space(1))) void*)gp,
        (__attribute__((address_space(3))) void*)lp, 16, 0, 0);
}

template <int BM, int BN, int WM, int WN, int ACT>
__global__ __launch_bounds__(WM * WN * 64)
void mgemm(const ushort* __restrict__ A1, const ushort* __restrict__ B1, int K1,
           const ushort* __restrict__ A2, const ushort* __restrict__ B2, int K2,
           const float* __restrict__ bias,
           ushort* __restrict__ C1, int ld1,
           ushort* __restrict__ C2, int ld2, int nsplit,
           int M, int N) {
    constexpr int NW = WM * WN;               // waves per block
    constexpr int MF = BM / (WM * 16);
    constexpr int NF = BN / (WN * 16);
    __shared__ char lds[(BM + BN) * 128];     // rows x 64 bf16, linear
    char* As = lds;
    char* Bs = lds + BM * 128;

    const int tid  = threadIdx.x;
    const int lane = tid & 63;
    const int wid  = tid >> 6;
    const int wm   = wid % WM, wn = wid / WM;
    const int bm   = blockIdx.x * BM;
    const int bn   = blockIdx.y * BN;
    const int l15  = lane & 15;
    const int lhi  = lane >> 4;
    const int lr8  = lane >> 3;               // row within 8-row gload group
    const int lf   = lane & 7;                // frag slot within row

    f32x4 acc[MF][NF] = {};

    for (int pass = 0; pass < 2; ++pass) {
        const ushort* A = pass ? A2 : A1;
        const ushort* B = pass ? B2 : B1;
        const int K = pass ? K2 : K1;
        if (A == nullptr) continue;
        for (int k0 = 0; k0 < K; k0 += 64) {
            #pragma unroll
            for (int it = 0; it < BM / (8 * NW); ++it) {     // stage A
                int r0 = (it * NW + wid) * 8;
                int row = r0 + lr8;
                int gr = bm + row; if (gr >= M) gr = M - 1;  // clamp; junk rows unused
                int gfc = lf ^ (row & 7);
                gload16(A + (size_t)gr * K + k0 + gfc * 8, As + r0 * 128);
            }
            #pragma unroll
            for (int it = 0; it < BN / (8 * NW); ++it) {     // stage B
                int r0 = (it * NW + wid) * 8;
                int row = r0 + lr8;
                int gfc = lf ^ (row & 7);
                gload16(B + (size_t)(bn + row) * K + k0 + gfc * 8, Bs + r0 * 128);
            }
            __syncthreads();
            #pragma unroll
            for (int ks = 0; ks < 2; ++ks) {
                const int kb = ks * 64 + lhi * 16;
                frag a[MF], b[NF];
                #pragma unroll
                for (int mf = 0; mf < MF; ++mf) {
                    int row = wm * MF * 16 + mf * 16 + l15;
                    a[mf] = *(const frag*)(As + row * 128 + (kb ^ ((row & 7) << 4)));
                }
                #pragma unroll
                for (int nf = 0; nf < NF; ++nf) {
                    int row = wn * NF * 16 + nf * 16 + l15;
                    b[nf] = *(const frag*)(Bs + row * 128 + (kb ^ ((row & 7) << 4)));
                }
                #pragma unroll
                for (int mf = 0; mf < MF; ++mf)
                    #pragma unroll
                    for (int nf = 0; nf < NF; ++nf)
                        acc[mf][nf] = __builtin_amdgcn_mfma_f32_16x16x32_bf16(
                            a[mf], b[nf], acc[mf][nf], 0, 0, 0);
            }
            __syncthreads();
        }
    }

    #pragma unroll
    for (int mf = 0; mf < MF; ++mf) {
        #pragma unroll
        for (int r = 0; r < 4; ++r) {
            int gm = bm + wm * MF * 16 + mf * 16 + lhi * 4 + r;
            if (gm >= M) continue;
            #pragma unroll
            for (int nf = 0; nf < NF; ++nf) {
                int gn = bn + wn * NF * 16 + nf * 16 + l15;
                float v = acc[mf][nf][r];
                if (bias) v += bias[gn];
                if (ACT == 1) v = fmaxf(v, 0.f);
                ushort o = f2bf(v);
                if (gn < nsplit) C1[(size_t)gm * ld1 + gn] = o;
                else             C2[(size_t)gm * ld2 + (gn - nsplit)] = o;
            }
        }
    }
}

// ---------------------------------------------------------------------------

extern "C" void kernel_launch(void* const* d_in, const int* in_sizes, int n_in,
                              void* d_out, int out_size, void* d_ws, size_t ws_size,
                              hipStream_t stream) {
    const float* x   = (const float*)d_in[0];
    const int*   ei  = (const int*)d_in[1];
    const float* Wl1 = (const float*)d_in[2];
    const float* Wr1 = (const float*)d_in[3];
    const float* b1  = (const float*)d_in[4];
    const float* Wl2 = (const float*)d_in[5];
    const float* Wr2 = (const float*)d_in[6];
    const float* b2  = (const float*)d_in[7];
    const float* Wl3 = (const float*)d_in[8];
    const float* Wr3 = (const float*)d_in[9];
    const float* b3  = (const float*)d_in[10];

    const int M = in_sizes[0] / 128;   // 50000
    const int E = in_sizes[1] / 2;     // 800000
    const int P = (M + PSZ - 1) / PSZ; // 98 partitions
    const int* src = ei;
    const int* dst = ei + E;

    char* w = (char*)d_ws;
    auto alloc = [&](size_t bytes) -> void* {
        void* p = (void*)w;
        w += (bytes + 255) & ~(size_t)255;
        return p;
    };
    int* pcount    = (int*)alloc((size_t)PMAX * 4);
    int* pbase     = (int*)alloc((size_t)(PMAX + 1) * 4);
    int* pcursor   = (int*)alloc((size_t)PMAX * 4);
    unsigned* pairs = (unsigned*)alloc((size_t)E * 4);
    ushort* csr16  = (ushort*)alloc((size_t)E * 2);
    int* deg       = (int*)alloc((size_t)M * 4);
    int* row_start = (int*)alloc((size_t)M * 4);
    ushort* Wl1t   = (ushort*)alloc(256 * 128 * 2);       // [256][128]
    ushort* Wr1t   = (ushort*)alloc(256 * 128 * 2);       // [256][128]
    ushort* Wcat2T = (ushort*)alloc(256 * 256 * 2);       // [256][256]: Wl2|Wr2 rows
    ushort* Wcat3T = (ushort*)alloc(128 * 128 * 2);       // [128][128]: Wl3|Wr3 rows
    ushort* bufA = (ushort*)alloc((size_t)M * 128 * 2);   // x_bf -> t2 -> t3
    ushort* bufB = (ushort*)alloc((size_t)M * 128 * 2);   // aggx -> h2
    ushort* bufH = (ushort*)alloc((size_t)M * 256 * 2);   // h1
    ushort* bufC = (ushort*)alloc((size_t)M * 128 * 2);   // u2 -> u3
    (void)ws_size; (void)n_in; (void)out_size;

    ushort* x_bf = bufA; ushort* t2 = bufA; ushort* t3 = bufA;
    ushort* aggx = bufB; ushort* h2 = bufB;
    ushort* h1 = bufH;
    ushort* u2 = bufC;   ushort* u3 = bufC;

    // CSR build: only pcount needs zeroing (<=512B)
    hipMemsetAsync(pcount, 0, (size_t)PMAX * 4, stream);
    const int nchunk = (E + 4095) / 4096;     // 196
    k_pcount<<<nchunk, 256, 0, stream>>>(dst, pcount, E, P);
    k_pscan<<<1, 64, 0, stream>>>(pcount, pbase, pcursor, P);
    k_scatter<<<nchunk, 256, 0, stream>>>(src, dst, pcursor, pairs, E, P);
    k_build<<<P, 256, 0, stream>>>(pairs, pbase, deg, row_start, csr16, M);

    // converts
    k_cvt_x<<<(M * 128 / 4 + 255) / 256, 256, 0, stream>>>(x, x_bf, M * 128 / 4);
    CvtDesc cd;
    cd.s[0] = Wl1; cd.d[0] = Wl1t;             cd.K[0] = 128; cd.N[0] = 256;
    cd.s[1] = Wr1; cd.d[1] = Wr1t;             cd.K[1] = 128; cd.N[1] = 256;
    cd.s[2] = Wl2; cd.d[2] = Wcat2T;           cd.K[2] = 256; cd.N[2] = 128;
    cd.s[3] = Wr2; cd.d[3] = Wcat2T + 128*256; cd.K[3] = 256; cd.N[3] = 128;
    cd.s[4] = Wl3; cd.d[4] = Wcat3T;           cd.K[4] = 128; cd.N[4] = 64;
    cd.s[5] = Wr3; cd.d[5] = Wcat3T + 64*128;  cd.K[5] = 128; cd.N[5] = 64;
    k_cvt_w6<<<dim3(128, 6), 256, 0, stream>>>(cd);

    const int gm128 = (M + 127) / 128;        // 391
    const int ga128 = (M + 7) / 8;            // 6250 (F=128: 8 nodes/block)
    const int ga64  = (M + 15) / 16;          // 3125 (F=64: 16 nodes/block)

    // ---- layer 1: aggx = agg(x); h1 = relu(aggx@Wl1 + x@Wr1 + b1)
    agg_bf<128, 0><<<ga128, 256, 0, stream>>>(x_bf, csr16, row_start, deg,
                                              nullptr, nullptr, aggx, M);
    mgemm<128, 64, 2, 2, 1><<<dim3(gm128, 4), 256, 0, stream>>>(
        aggx, Wl1t, 128, x_bf, Wr1t, 128, b1,
        h1, 256, nullptr, 0, 256, M, 256);

    // ---- layer 2: [t2|u2] = h1@Wcat2; h2 = relu(agg(t2) + u2 + b2)
    mgemm<128, 64, 2, 2, 0><<<dim3(gm128, 4), 256, 0, stream>>>(
        h1, Wcat2T, 256, nullptr, nullptr, 0, nullptr,
        t2, 128, u2, 128, 128, M, 256);
    agg_bf<128, 1><<<ga128, 256, 0, stream>>>(t2, csr16, row_start, deg,
                                              u2, b2, h2, M);

    // ---- layer 3: [t3|u3] = h2@Wcat3; out = sigmoid(agg(t3) + u3 + b3)
    mgemm<128, 64, 2, 2, 0><<<dim3(gm128, 2), 256, 0, stream>>>(
        h2, Wcat3T, 128, nullptr, nullptr, 0, nullptr,
        t3, 64, u3, 64, 64, M, 128);
    agg_bf<64, 2><<<ga64, 256, 0, stream>>>(t3, csr16, row_start, deg,
                                            u3, b3, (float*)d_out, M);
}

// Round 14
// 211.271 us; speedup vs baseline: 1.1090x; 1.0211x over previous
//
#include <hip/hip_runtime.h>
#include <cstddef>

// ---------------------------------------------------------------------------
// SAGEBlock: 3-layer GraphSAGE (mean aggr), N=50000, E=800000.
//   h1 = relu(agg(x)@Wl1 + x@Wr1 + b1)              128 -> 256
//   h2 = relu(agg(h1@Wl2) + h1@Wr2 + b2)            256 -> 128
//   out= sigmoid(agg(h2@Wl3) + h2@Wr3 + b3)         128 -> 64
// R14: software-pipelined mgemm (double-buffered LDS, ONE barrier per K-step,
//     prefetch next K-tile during compute -> hides global latency; T3-lite).
//     Layer 1 folded to a single K=256 GEMM via interleaved AX=[agg|x] buffer
//     (agg1/cvt_x write strided halves; Wcat1T = K-concat of Wl1,Wr1).
//     CSR counting sort (R10) + F/4-lane agg (R11) + gload_lds (R13) kept.
// ---------------------------------------------------------------------------

using frag  = __attribute__((ext_vector_type(8))) short;   // 8 bf16
using f32x4 = __attribute__((ext_vector_type(4))) float;

constexpr int PBITS = 9;                 // 512 nodes per partition
constexpr int PSZ   = 1 << PBITS;
constexpr int PMAX  = 128;               // max partitions (M <= 65536)

__device__ __forceinline__ ushort f2bf(float f) {
    union { float f; unsigned u; } v; v.f = f;
    unsigned r = v.u + 0x7FFF + ((v.u >> 16) & 1);   // RNE
    return (ushort)(r >> 16);
}
__device__ __forceinline__ float bf2f(ushort u) {
    union { unsigned u; float f; } v; v.u = ((unsigned)u) << 16;
    return v.f;
}

// ---------------- CSR build: counting sort by partition ----------------

__global__ __launch_bounds__(256)
void k_pcount(const int* __restrict__ dst, int* __restrict__ pcount, int E, int P) {
    __shared__ int h[PMAX];
    int t = threadIdx.x;
    if (t < P) h[t] = 0;
    __syncthreads();
    int base = blockIdx.x * 4096;
    int n = min(4096, E - base);
    for (int i = t; i < n; i += 256)
        atomicAdd(&h[dst[base + i] >> PBITS], 1);
    __syncthreads();
    if (t < P && h[t]) atomicAdd(&pcount[t], h[t]);
}

__global__ void k_pscan(const int* __restrict__ pcount, int* __restrict__ pbase,
                        int* __restrict__ pcursor, int P) {
    if (threadIdx.x == 0) {
        int run = 0;
        for (int p = 0; p < P; ++p) { pbase[p] = run; pcursor[p] = run; run += pcount[p]; }
        pbase[P] = run;
    }
}

__global__ __launch_bounds__(256)
void k_scatter(const int* __restrict__ src, const int* __restrict__ dst,
               int* __restrict__ pcursor, unsigned* __restrict__ pairs, int E, int P) {
    __shared__ int h[PMAX];
    __shared__ int off[PMAX];
    int t = threadIdx.x;
    if (t < P) h[t] = 0;
    __syncthreads();
    int base = blockIdx.x * 4096;
    int pp[16]; int pr[16]; unsigned pk[16];
    #pragma unroll
    for (int ii = 0; ii < 16; ++ii) {          // static index -> stays in VGPRs
        int idx = base + ii * 256 + t;
        bool v = idx < E;
        int d = v ? dst[idx] : 0;
        int p = d >> PBITS;
        pp[ii] = v ? p : -1;
        pr[ii] = v ? atomicAdd(&h[p], 1) : 0;
        pk[ii] = v ? ((unsigned)src[idx] | ((unsigned)(d & (PSZ - 1)) << 16)) : 0u;
    }
    __syncthreads();
    if (t < P && h[t]) off[t] = atomicAdd(&pcursor[t], h[t]);
    __syncthreads();
    #pragma unroll
    for (int ii = 0; ii < 16; ++ii)
        if (pp[ii] >= 0) pairs[off[pp[ii]] + pr[ii]] = pk[ii];
}

__global__ __launch_bounds__(256)
void k_build(const unsigned* __restrict__ pairs, const int* __restrict__ pbase,
             int* __restrict__ deg, int* __restrict__ row_start,
             ushort* __restrict__ csr16, int M) {
    __shared__ int cnt[PSZ];
    __shared__ int ls[PSZ];
    __shared__ int fil[PSZ];
    __shared__ int ws[256];
    int pid = blockIdx.x;
    int t = threadIdx.x;
    int n0 = pid << PBITS;
    int L = min(PSZ, M - n0);
    int wb = pbase[pid], we = pbase[pid + 1];
    int ne = we - wb;
    for (int j = t; j < PSZ; j += 256) { cnt[j] = 0; fil[j] = 0; }
    __syncthreads();
    for (int i = t; i < ne; i += 256)
        atomicAdd(&cnt[pairs[wb + i] >> 16], 1);
    __syncthreads();
    int a = cnt[2 * t], b = cnt[2 * t + 1];
    ws[t] = a + b;
    __syncthreads();
    for (int o = 1; o < 256; o <<= 1) {
        int v = (t >= o) ? ws[t - o] : 0;
        __syncthreads();
        ws[t] += v;
        __syncthreads();
    }
    int excl = (t > 0) ? ws[t - 1] : 0;
    ls[2 * t] = excl; ls[2 * t + 1] = excl + a;
    __syncthreads();
    for (int j = t; j < L; j += 256) {
        deg[n0 + j] = cnt[j];
        row_start[n0 + j] = wb + ls[j];
    }
    for (int i = t; i < ne; i += 256) {
        unsigned pk = pairs[wb + i];
        int ln = pk >> 16;
        int pos = wb + ls[ln] + atomicAdd(&fil[ln], 1);
        csr16[pos] = (ushort)(pk & 0xFFFFu);
    }
}

// ---------------- dtype converts ----------------

// x[M][128] f32 -> AX[M][256] bf16 cols 128..255 (agg fills cols 0..127)
__global__ void k_cvt_x(const float* __restrict__ in, ushort* __restrict__ AX, int n4) {
    int i = blockIdx.x * blockDim.x + threadIdx.x;
    if (i < n4) {
        int row = i >> 5;            // 32 float4 per row of 128
        int c4  = i & 31;
        float4 v = ((const float4*)in)[i];
        ushort4 o; o.x = f2bf(v.x); o.y = f2bf(v.y); o.z = f2bf(v.z); o.w = f2bf(v.w);
        *(ushort4*)(AX + (size_t)row * 256 + 128 + c4 * 4) = o;
    }
}

struct CvtDesc {
    const float* s[6];
    ushort*      d[6];
    int K[6];    // src K
    int N[6];    // src N
    int KD[6];   // dst row stride
    int KO[6];   // dst k offset
};

__global__ void k_cvt_w6(CvtDesc c) {
    int wi = blockIdx.y;
    int t = blockIdx.x * blockDim.x + threadIdx.x;
    int K = c.K[wi], N = c.N[wi];
    if (t < K * N) {
        int k = t / N, n = t % N;
        c.d[wi][(size_t)n * c.KD[wi] + c.KO[wi] + k] = f2bf(c.s[wi][t]);
    }
}

// ---------------- mean aggregation + fused epilogue ----------------
// F/4 lanes per node, ushort4 (8B) per lane. LDI/LDO: row strides (ushorts).
// EPI: 0 = plain bf16 out; 1 = relu(agg+u+b) bf16 out; 2 = sigmoid(agg+u+b) f32 out

template <int F, int EPI, int LDI, int LDO>
__global__ __launch_bounds__(256)
void agg_bf(const ushort* __restrict__ in, const ushort* __restrict__ csr16,
            const int* __restrict__ row_start, const int* __restrict__ deg,
            const ushort* __restrict__ u, const float* __restrict__ bias,
            void* __restrict__ out, int nN) {
    constexpr int GPL = F / 4;                 // lanes per node
    constexpr int NPB = 256 / GPL;             // nodes per block
    int gid  = threadIdx.x / GPL;
    int li   = threadIdx.x % GPL;
    int node = blockIdx.x * NPB + gid;
    bool valid = node < nN;
    int start = valid ? row_start[node] : 0;
    int d     = valid ? deg[node] : 0;
    float a0 = 0.f, a1 = 0.f, a2 = 0.f, a3 = 0.f;

    auto gat = [&](int j) {
        int s = csr16[start + j];
        ushort4 uv = *(const ushort4*)(in + (size_t)s * LDI + li * 4);
        a0 += bf2f(uv.x); a1 += bf2f(uv.y); a2 += bf2f(uv.z); a3 += bf2f(uv.w);
    };

    int j = 0;
    for (; j + 8 <= d; j += 8) {
        gat(j); gat(j+1); gat(j+2); gat(j+3);
        gat(j+4); gat(j+5); gat(j+6); gat(j+7);
    }
    for (; j + 2 <= d; j += 2) { gat(j); gat(j+1); }
    for (; j < d; ++j) gat(j);

    if (!valid) return;
    float inv = 1.f / (float)(d > 0 ? d : 1);
    a0 *= inv; a1 *= inv; a2 *= inv; a3 *= inv;

    size_t o4 = (size_t)node * LDO + li * 4;
    if constexpr (EPI == 0) {
        ushort4 o; o.x = f2bf(a0); o.y = f2bf(a1); o.z = f2bf(a2); o.w = f2bf(a3);
        *(ushort4*)((ushort*)out + o4) = o;
    } else {
        ushort4 uv = *(const ushort4*)(u + (size_t)node * F + li * 4);
        float4 bv = *(const float4*)(bias + li * 4);
        a0 += bf2f(uv.x) + bv.x;
        a1 += bf2f(uv.y) + bv.y;
        a2 += bf2f(uv.z) + bv.z;
        a3 += bf2f(uv.w) + bv.w;
        if constexpr (EPI == 1) {
            ushort4 o;
            o.x = f2bf(fmaxf(a0, 0.f)); o.y = f2bf(fmaxf(a1, 0.f));
            o.z = f2bf(fmaxf(a2, 0.f)); o.w = f2bf(fmaxf(a3, 0.f));
            *(ushort4*)((ushort*)out + o4) = o;
        } else {
            float4 o;
            o.x = 1.f / (1.f + __expf(-a0)); o.y = 1.f / (1.f + __expf(-a1));
            o.z = 1.f / (1.f + __expf(-a2)); o.w = 1.f / (1.f + __expf(-a3));
            *(float4*)((float*)out + o4) = o;
        }
    }
}

// ---------------- bf16 MFMA GEMM: 2-phase pipelined, gload_lds staging ------
// C[M,N] = act( A@B^T (+ bias) ); col < nsplit -> C1, else C2.
// A: [M][K] bf16. B: [N][K] bf16 (pre-transposed). Double-buffered LDS,
// ONE barrier per K-step; prefetch of step s+1 overlaps compute of step s.
// Swizzle: linear LDS dest + inverse-XOR global source (rule #21).

__device__ __forceinline__ void gload16(const ushort* gp, char* lp) {
    __builtin_amdgcn_global_load_lds(
        (const __attribute__((address_space(1))) void*)gp,
        (__attribute__((address_space(3))) void*)lp, 16, 0, 0);
}

template <int BM, int BN, int K, int ACT>
__global__ __launch_bounds__(256)
void mgemm(const ushort* __restrict__ A, const ushort* __restrict__ B,
           const float* __restrict__ bias,
           ushort* __restrict__ C1, int ld1,
           ushort* __restrict__ C2, int ld2, int nsplit,
           int M, int N) {
    constexpr int NW = 4;                     // waves per block
    constexpr int WM = 2, WN = 2;
    constexpr int MF = BM / (WM * 16);
    constexpr int NF = BN / (WN * 16);
    constexpr int NSTEP = K / 64;
    constexpr int TB = (BM + BN) * 128;       // bytes per buffer
    __shared__ char lds[2 * TB];

    const int tid  = threadIdx.x;
    const int lane = tid & 63;
    const int wid  = tid >> 6;
    const int wm   = wid % WM, wn = wid / WM;
    const int bm   = blockIdx.x * BM;
    const int bn   = blockIdx.y * BN;
    const int l15  = lane & 15;
    const int lhi  = lane >> 4;
    const int lr8  = lane >> 3;               // row within 8-row gload group
    const int lf   = lane & 7;                // frag slot within row

    auto stage = [&](int buf, int k0) {
        char* As = lds + buf * TB;
        char* Bs = As + BM * 128;
        #pragma unroll
        for (int it = 0; it < BM / (8 * NW); ++it) {
            int r0 = (it * NW + wid) * 8;
            int row = r0 + lr8;
            int gr = bm + row; if (gr >= M) gr = M - 1;   // clamp; junk rows unused
            int gfc = lf ^ (row & 7);
            gload16(A + (size_t)gr * K + k0 + gfc * 8, As + r0 * 128);
        }
        #pragma unroll
        for (int it = 0; it < BN / (8 * NW); ++it) {
            int r0 = (it * NW + wid) * 8;
            int row = r0 + lr8;
            int gfc = lf ^ (row & 7);
            gload16(B + (size_t)(bn + row) * K + k0 + gfc * 8, Bs + r0 * 128);
        }
    };

    f32x4 acc[MF][NF] = {};

    stage(0, 0);
    #pragma unroll
    for (int s = 0; s < NSTEP; ++s) {
        __syncthreads();                       // drains stage(s); compiler emits vmcnt(0)
        if (s + 1 < NSTEP) stage((s + 1) & 1, (s + 1) * 64);   // prefetch overlaps compute
        char* As = lds + (s & 1) * TB;
        char* Bs = As + BM * 128;
        #pragma unroll
        for (int ks = 0; ks < 2; ++ks) {
            const int kb = ks * 64 + lhi * 16;
            frag a[MF], b[NF];
            #pragma unroll
            for (int mf = 0; mf < MF; ++mf) {
                int row = wm * MF * 16 + mf * 16 + l15;
                a[mf] = *(const frag*)(As + row * 128 + (kb ^ ((row & 7) << 4)));
            }
            #pragma unroll
            for (int nf = 0; nf < NF; ++nf) {
                int row = wn * NF * 16 + nf * 16 + l15;
                b[nf] = *(const frag*)(Bs + row * 128 + (kb ^ ((row & 7) << 4)));
            }
            #pragma unroll
            for (int mf = 0; mf < MF; ++mf)
                #pragma unroll
                for (int nf = 0; nf < NF; ++nf)
                    acc[mf][nf] = __builtin_amdgcn_mfma_f32_16x16x32_bf16(
                        a[mf], b[nf], acc[mf][nf], 0, 0, 0);
        }
    }

    #pragma unroll
    for (int mf = 0; mf < MF; ++mf) {
        #pragma unroll
        for (int r = 0; r < 4; ++r) {
            int gm = bm + wm * MF * 16 + mf * 16 + lhi * 4 + r;
            if (gm >= M) continue;
            #pragma unroll
            for (int nf = 0; nf < NF; ++nf) {
                int gn = bn + wn * NF * 16 + nf * 16 + l15;
                float v = acc[mf][nf][r];
                if (bias) v += bias[gn];
                if (ACT == 1) v = fmaxf(v, 0.f);
                ushort o = f2bf(v);
                if (gn < nsplit) C1[(size_t)gm * ld1 + gn] = o;
                else             C2[(size_t)gm * ld2 + (gn - nsplit)] = o;
            }
        }
    }
}

// ---------------------------------------------------------------------------

extern "C" void kernel_launch(void* const* d_in, const int* in_sizes, int n_in,
                              void* d_out, int out_size, void* d_ws, size_t ws_size,
                              hipStream_t stream) {
    const float* x   = (const float*)d_in[0];
    const int*   ei  = (const int*)d_in[1];
    const float* Wl1 = (const float*)d_in[2];
    const float* Wr1 = (const float*)d_in[3];
    const float* b1  = (const float*)d_in[4];
    const float* Wl2 = (const float*)d_in[5];
    const float* Wr2 = (const float*)d_in[6];
    const float* b2  = (const float*)d_in[7];
    const float* Wl3 = (const float*)d_in[8];
    const float* Wr3 = (const float*)d_in[9];
    const float* b3  = (const float*)d_in[10];

    const int M = in_sizes[0] / 128;   // 50000
    const int E = in_sizes[1] / 2;     // 800000
    const int P = (M + PSZ - 1) / PSZ; // 98 partitions
    const int* src = ei;
    const int* dst = ei + E;

    char* w = (char*)d_ws;
    auto alloc = [&](size_t bytes) -> void* {
        void* p = (void*)w;
        w += (bytes + 255) & ~(size_t)255;
        return p;
    };
    int* pcount    = (int*)alloc((size_t)PMAX * 4);
    int* pbase     = (int*)alloc((size_t)(PMAX + 1) * 4);
    int* pcursor   = (int*)alloc((size_t)PMAX * 4);
    unsigned* pairs = (unsigned*)alloc((size_t)E * 4);
    ushort* csr16  = (ushort*)alloc((size_t)E * 2);
    int* deg       = (int*)alloc((size_t)M * 4);
    int* row_start = (int*)alloc((size_t)M * 4);
    ushort* Wcat1T = (ushort*)alloc(256 * 256 * 2);       // [256 n][256 k]: Wl1|Wr1 (K-concat)
    ushort* Wcat2T = (ushort*)alloc(256 * 256 * 2);       // [256 n][256 k]: Wl2|Wr2 (N-concat)
    ushort* Wcat3T = (ushort*)alloc(128 * 128 * 2);       // [128 n][128 k]: Wl3|Wr3 (N-concat)
    ushort* AX   = (ushort*)alloc((size_t)M * 256 * 2);   // [aggx | x_bf] interleaved
    ushort* bufA = (ushort*)alloc((size_t)M * 128 * 2);   // t2 -> t3
    ushort* bufB = (ushort*)alloc((size_t)M * 128 * 2);   // h2
    ushort* bufH = (ushort*)alloc((size_t)M * 256 * 2);   // h1
    ushort* bufC = (ushort*)alloc((size_t)M * 128 * 2);   // u2 -> u3
    (void)ws_size; (void)n_in; (void)out_size;

    ushort* t2 = bufA; ushort* t3 = bufA;
    ushort* h2 = bufB;
    ushort* h1 = bufH;
    ushort* u2 = bufC;   ushort* u3 = bufC;

    // CSR build: only pcount needs zeroing (<=512B)
    hipMemsetAsync(pcount, 0, (size_t)PMAX * 4, stream);
    const int nchunk = (E + 4095) / 4096;     // 196
    k_pcount<<<nchunk, 256, 0, stream>>>(dst, pcount, E, P);
    k_pscan<<<1, 64, 0, stream>>>(pcount, pbase, pcursor, P);
    k_scatter<<<nchunk, 256, 0, stream>>>(src, dst, pcursor, pairs, E, P);
    k_build<<<P, 256, 0, stream>>>(pairs, pbase, deg, row_start, csr16, M);

    // converts
    k_cvt_x<<<(M * 128 / 4 + 255) / 256, 256, 0, stream>>>(x, AX, M * 128 / 4);
    CvtDesc cd;
    cd.s[0] = Wl1; cd.d[0] = Wcat1T;           cd.K[0] = 128; cd.N[0] = 256; cd.KD[0] = 256; cd.KO[0] = 0;
    cd.s[1] = Wr1; cd.d[1] = Wcat1T;           cd.K[1] = 128; cd.N[1] = 256; cd.KD[1] = 256; cd.KO[1] = 128;
    cd.s[2] = Wl2; cd.d[2] = Wcat2T;           cd.K[2] = 256; cd.N[2] = 128; cd.KD[2] = 256; cd.KO[2] = 0;
    cd.s[3] = Wr2; cd.d[3] = Wcat2T + 128*256; cd.K[3] = 256; cd.N[3] = 128; cd.KD[3] = 256; cd.KO[3] = 0;
    cd.s[4] = Wl3; cd.d[4] = Wcat3T;           cd.K[4] = 128; cd.N[4] = 64;  cd.KD[4] = 128; cd.KO[4] = 0;
    cd.s[5] = Wr3; cd.d[5] = Wcat3T + 64*128;  cd.K[5] = 128; cd.N[5] = 64;  cd.KD[5] = 128; cd.KO[5] = 0;
    k_cvt_w6<<<dim3(128, 6), 256, 0, stream>>>(cd);

    const int gm64 = (M + 63) / 64;           // 782
    const int ga128 = (M + 7) / 8;            // 6250 (F=128: 8 nodes/block)
    const int ga64  = (M + 15) / 16;          // 3125 (F=64: 16 nodes/block)

    // ---- layer 1: aggx (cols 0..127 of AX) = agg(x from cols 128..255);
    //      h1 = relu(AX @ Wcat1T + b1)   [single K=256 GEMM]
    agg_bf<128, 0, 256, 256><<<ga128, 256, 0, stream>>>(
        AX + 128, csr16, row_start, deg, nullptr, nullptr, AX, M);
    mgemm<64, 64, 256, 1><<<dim3(gm64, 4), 256, 0, stream>>>(
        AX, Wcat1T, b1, h1, 256, h1, 256, 256, M, 256);

    // ---- layer 2: [t2|u2] = h1@Wcat2; h2 = relu(agg(t2) + u2 + b2)
    mgemm<64, 64, 256, 0><<<dim3(gm64, 4), 256, 0, stream>>>(
        h1, Wcat2T, nullptr, t2, 128, u2, 128, 128, M, 256);
    agg_bf<128, 1, 128, 128><<<ga128, 256, 0, stream>>>(
        t2, csr16, row_start, deg, u2, b2, h2, M);

    // ---- layer 3: [t3|u3] = h2@Wcat3; out = sigmoid(agg(t3) + u3 + b3)
    mgemm<64, 64, 128, 0><<<dim3(gm64, 2), 256, 0, stream>>>(
        h2, Wcat3T, nullptr, t3, 64, u3, 64, 64, M, 128);
    agg_bf<64, 2, 64, 64><<<ga64, 256, 0, stream>>>(
        t3, csr16, row_start, deg, u3, b3, (float*)d_out, M);
}